// Round 14
// baseline (237.576 us; speedup 1.0000x reference)
//
#include <hip/hip_runtime.h>

// MultiHeadAttention: B=4, S=2048, D_IN=1024, H=16, d=64, D_OUT=1024, f32 I/O.
// attn v13 = R12-proven v9 body with HARDENED SYNC ONLY: every __syncthreads()
// in attn_k replaced by an explicit fence {sched_barrier(0); s_waitcnt
// vmcnt(0) lgkmcnt(0) (memory clobber); sched_barrier(0); s_barrier;
// sched_barrier(0)}. Rationale: exact v9 passes (twice); three independent
// semantically-sound edits all failed with a garbage-K-staging signature
// (softmax delta -> output = raw V row, absmax ~4.4) => schedule-dependent
// race in the gl16 dbuf staging around the implicit barrier drain. The fence
// makes the drain + no-code-motion explicit. Compute body byte-identical.
// gemm2_k / prep_k untouched (never failed; IR unchanged across rounds).
// Workspace (74 MB), staged aliasing (order matters: V-GEMM -> K-GEMM -> Q-GEMM):
//   [0,8M)    Wq^T,Wk^T,Wv^T,Wo^T bf16 (head-major permuted: c=d*16+h -> h*64+d)
//   [8,10M)   mask bitwords u64 [B][S][S/64]
//   [10,26M)  X2 = keys bf16   -> later Qh bf16 [bh][s][64] (scaled log2e/8)
//   [26,42M)  X3 = values bf16 -> later Kh tiles: (bh,ts) 8KB, byte=key*128+((2d)^((key&7)<<4))
//   [42,58M)  Vt tiles: (bh,ts) 8KB, byte=d*128+((2key)^((d&7)<<4))
//   [58,74M)  X1 = queries bf16 -> later Mha bf16 [b][s][h*64+d]

typedef __bf16 bf16x8 __attribute__((ext_vector_type(8)));
typedef __bf16 bf16x4 __attribute__((ext_vector_type(4)));
typedef float f32x4 __attribute__((ext_vector_type(4)));

__device__ __forceinline__ unsigned short f2bf(float f) {
  union { float f; unsigned u; } x; x.f = f;
  unsigned r = x.u + 0x7fffu + ((x.u >> 16) & 1u);   // RNE
  return (unsigned short)(r >> 16);
}

__device__ __forceinline__ float exp2fast(float x) {
#if __has_builtin(__builtin_amdgcn_exp2f)
  return __builtin_amdgcn_exp2f(x);
#else
  return exp2f(x);
#endif
}

__device__ __forceinline__ f32x4 mfma16(bf16x8 a, bf16x8 b, f32x4 c) {
  return __builtin_amdgcn_mfma_f32_16x16x32_bf16(a, b, c, 0, 0, 0);
}

__device__ __forceinline__ void gl16(const void* g, void* l) {
  __builtin_amdgcn_global_load_lds(
      (const __attribute__((address_space(1))) unsigned int*)g,
      (__attribute__((address_space(3))) unsigned int*)l, 16, 0, 0);
}

// Hardened barrier: explicit drain + scheduling fences on both sides.
// Does not rely on compiler's implicit vmcnt(0) insertion before s_barrier,
// and forbids any code motion across the barrier region (rule #18 compliant).
__device__ __forceinline__ void hard_sync() {
  __builtin_amdgcn_sched_barrier(0);
  asm volatile("s_waitcnt vmcnt(0) lgkmcnt(0)" ::: "memory");
  __builtin_amdgcn_sched_barrier(0);
  __builtin_amdgcn_s_barrier();
  __builtin_amdgcn_sched_barrier(0);
}

// pack 2 f32 -> bf16x2 word (RNE), single instruction
__device__ __forceinline__ unsigned cvtpk(float lo, float hi) {
  unsigned r;
  asm("v_cvt_pk_bf16_f32 %0, %1, %2" : "=v"(r) : "v"(lo), "v"(hi));
  return r;
}
__device__ __forceinline__ void swap32(unsigned &a, unsigned &b) {
  asm("v_permlane32_swap_b32 %0, %1" : "+v"(a), "+v"(b));
}
__device__ __forceinline__ void swap16(unsigned &a, unsigned &b) {
  asm("v_permlane16_swap_b32 %0, %1" : "+v"(a), "+v"(b));
}

// perm: c = d*16+h  ->  c' = h*64+d
__device__ __forceinline__ int permf(int x) { return ((x & 15) << 6) | (x >> 4); }
__device__ __forceinline__ int ipermf(int x) { return ((x & 63) << 4) | (x >> 6); }

// ---------- merged prep: maskbits | f32->bf16 cvt | weight transposes ----------
// grid: [0,65536) maskbits, [65536,77824) cvt (3 x 4096), [77824,81920) wtrans (4 x 1024)
__global__ __launch_bounds__(256) void prep_k(const float* __restrict__ q,
                                              const float* __restrict__ k,
                                              const float* __restrict__ v,
                                              const int* __restrict__ mask,
                                              const float* __restrict__ W0,
                                              const float* __restrict__ W1,
                                              const float* __restrict__ W2,
                                              const float* __restrict__ W3,
                                              unsigned short* __restrict__ T0,
                                              unsigned short* __restrict__ T1,
                                              unsigned short* __restrict__ T2,
                                              unsigned short* __restrict__ T3,
                                              unsigned long long* __restrict__ mb,
                                              unsigned short* __restrict__ o0,
                                              unsigned short* __restrict__ o1,
                                              unsigned short* __restrict__ o2) {
  __shared__ float sh[32][33];
  const int id = blockIdx.x, t = threadIdx.x;
  if (id < 65536) {           // ---- mask -> bitwords ----
    long i = (long)id * 256 + t;
    unsigned long long b = __ballot(mask[i] != 0);
    if ((t & 63) == 0) mb[i >> 6] = b;
  } else if (id < 77824) {    // ---- f32 -> bf16 x8 ----
    int id2 = id - 65536;
    int which = id2 >> 12, x = id2 & 4095;
    const float* in = which == 0 ? q : which == 1 ? k : v;
    unsigned short* out = which == 0 ? o0 : which == 1 ? o1 : o2;
    long i = ((long)x * 256 + t) * 8;
    float4 a = *(const float4*)(in + i);
    float4 b4 = *(const float4*)(in + i + 4);
    union { bf16x8 v8; uint4 u; } o;
    o.v8[0] = (__bf16)a.x; o.v8[1] = (__bf16)a.y; o.v8[2] = (__bf16)a.z; o.v8[3] = (__bf16)a.w;
    o.v8[4] = (__bf16)b4.x; o.v8[5] = (__bf16)b4.y; o.v8[6] = (__bf16)b4.z; o.v8[7] = (__bf16)b4.w;
    *(uint4*)(out + i) = o.u;
  } else {                    // ---- weight transpose (+ head-major perm) ----
    int id3 = id - 77824;
    int z = id3 >> 10, rem = id3 & 1023;
    int n0 = (rem & 31) * 32, k0 = (rem >> 5) * 32;
    const float* W = z == 0 ? W0 : z == 1 ? W1 : z == 2 ? W2 : W3;
    unsigned short* T = z == 0 ? T0 : z == 1 ? T1 : z == 2 ? T2 : T3;
    int tx = t & 31, ty = t >> 5;   // 32x8
#pragma unroll
    for (int r = 0; r < 32; r += 8) {
      int srow = (z == 3) ? ipermf(k0 + ty + r) : (k0 + ty + r);
      sh[ty + r][tx] = W[(long)srow * 1024 + n0 + tx];
    }
    __syncthreads();
#pragma unroll
    for (int r = 0; r < 32; r += 8) {
      int drow = (z < 3) ? permf(n0 + ty + r) : (n0 + ty + r);
      T[(long)drow * 1024 + k0 + tx] = f2bf(sh[tx][ty + r]);
    }
  }
}

// ---------- GEMM m97-style: A bf16 [8192x1024] @ Wt^T, BK=64, dbuf gl16 ----------
template <int OUTMODE>
__global__ __launch_bounds__(256, 2) void gemm2_k(const unsigned short* __restrict__ A,
                                                  const unsigned short* __restrict__ Bt,
                                                  void* __restrict__ Out, float scale) {
  __shared__ __align__(16) char lds[2][32768];   // [buf][ A 16KB | B 16KB ]
  const int t = threadIdx.x, lane = t & 63, wv = t >> 6;
  const int wm = wv >> 1, wn = wv & 1;           // 2x2 waves, 64x64 each
  const int id = blockIdx.x;                     // 512 blocks, XCD-swizzled
  const int logical = (id & 7) * 64 + (id >> 3);
  const int i0 = (logical >> 3) * 128, n0 = (logical & 7) * 128;
  const int lr = lane & 15, lg = lane >> 4;

  long aoff[4], boff[4];
#pragma unroll
  for (int j = 0; j < 4; ++j) {
    int c = j * 256 + t, r = c >> 3, kc = (c & 7) ^ (r & 7);
    aoff[j] = ((long)(i0 + r) << 10) + kc * 8;
    boff[j] = ((long)(n0 + r) << 10) + kc * 8;
  }

  f32x4 zero = {0.f, 0.f, 0.f, 0.f};
  f32x4 acc[4][4];
#pragma unroll
  for (int mt = 0; mt < 4; ++mt)
#pragma unroll
    for (int nt = 0; nt < 4; ++nt) acc[mt][nt] = zero;

#pragma unroll
  for (int j = 0; j < 4; ++j) {
    gl16(A + aoff[j], &lds[0][j * 4096 + wv * 1024]);
    gl16(Bt + boff[j], &lds[0][16384 + j * 4096 + wv * 1024]);
  }
  __syncthreads();

  for (int ks = 0; ks < 16; ++ks) {
    const int cur = ks & 1;
    if (ks + 1 < 16) {
      const unsigned short* Ak = A + (ks + 1) * 64;
      const unsigned short* Bk = Bt + (ks + 1) * 64;
#pragma unroll
      for (int j = 0; j < 4; ++j) {
        gl16(Ak + aoff[j], &lds[cur ^ 1][j * 4096 + wv * 1024]);
        gl16(Bk + boff[j], &lds[cur ^ 1][16384 + j * 4096 + wv * 1024]);
      }
    }
    const char* Ab = &lds[cur][0];
    const char* Bb = &lds[cur][16384];
    bf16x8 af[2][4], bfr[2][4];
#pragma unroll
    for (int mt = 0; mt < 4; ++mt) {
      int r = wm * 64 + mt * 16 + lr;
      int sw = (r & 7) << 4;
      af[0][mt] = *(const bf16x8*)(Ab + r * 128 + ((lg * 16) ^ sw));
      af[1][mt] = *(const bf16x8*)(Ab + r * 128 + ((64 + lg * 16) ^ sw));
    }
#pragma unroll
    for (int nt = 0; nt < 4; ++nt) {
      int r = wn * 64 + nt * 16 + lr;
      int sw = (r & 7) << 4;
      bfr[0][nt] = *(const bf16x8*)(Bb + r * 128 + ((lg * 16) ^ sw));
      bfr[1][nt] = *(const bf16x8*)(Bb + r * 128 + ((64 + lg * 16) ^ sw));
    }
#pragma unroll
    for (int h2 = 0; h2 < 2; ++h2)
#pragma unroll
      for (int mt = 0; mt < 4; ++mt)
#pragma unroll
        for (int nt = 0; nt < 4; ++nt)
          acc[mt][nt] = mfma16(af[h2][mt], bfr[h2][nt], acc[mt][nt]);
    __syncthreads();
  }

  if (OUTMODE == 2) {
    float* O = (float*)Out;
#pragma unroll
    for (int mt = 0; mt < 4; ++mt)
#pragma unroll
      for (int nt = 0; nt < 4; ++nt)
#pragma unroll
        for (int r = 0; r < 4; ++r) {
          int row = i0 + wm * 64 + mt * 16 + lg * 4 + r;
          int col = n0 + wn * 64 + nt * 16 + lr;
          O[(long)row * 1024 + col] = acc[mt][nt][r];
        }
  } else if (OUTMODE == 0) {  // Qh [bh][s][64]
    unsigned short* O = (unsigned short*)Out;
#pragma unroll
    for (int mt = 0; mt < 4; ++mt)
#pragma unroll
      for (int nt = 0; nt < 4; ++nt) {
        int col = n0 + wn * 64 + nt * 16 + lr;
        int h = col >> 6, d = col & 63;
#pragma unroll
        for (int r = 0; r < 4; ++r) {
          int row = i0 + wm * 64 + mt * 16 + lg * 4 + r;
          int b = row >> 11, s = row & 2047;
          O[(((long)(b * 16 + h) * 2048 + s) << 6) + d] = f2bf(acc[mt][nt][r] * scale);
        }
      }
  } else if (OUTMODE == 3) {  // K tiles
    char* O = (char*)Out;
#pragma unroll
    for (int mt = 0; mt < 4; ++mt)
#pragma unroll
      for (int nt = 0; nt < 4; ++nt) {
        int col = n0 + wn * 64 + nt * 16 + lr;
        int h = col >> 6, d = col & 63;
#pragma unroll
        for (int r = 0; r < 4; ++r) {
          int row = i0 + wm * 64 + mt * 16 + lg * 4 + r;
          int b = row >> 11, s = row & 2047;
          int bh = b * 16 + h, ts = s >> 6, key = s & 63;
          long byte = ((long)(bh * 32 + ts) << 13) + key * 128 + ((d * 2) ^ ((key & 7) << 4));
          unsigned short bv = f2bf(acc[mt][nt][r]);
          *(unsigned short*)(O + byte) = bv;
        }
      }
  } else {  // OUTMODE 4: V tiles
    char* O = (char*)Out;
#pragma unroll
    for (int mt = 0; mt < 4; ++mt)
#pragma unroll
      for (int nt = 0; nt < 4; ++nt) {
        int col = n0 + wn * 64 + nt * 16 + lr;
        int h = col >> 6, d = col & 63;
        int row0 = i0 + wm * 64 + mt * 16 + lg * 4;
        int b = row0 >> 11, s0 = row0 & 2047;
        int bh = b * 16 + h, ts = s0 >> 6, key0 = s0 & 63;
        ushort4 w;
        w.x = f2bf(acc[mt][nt][0]); w.y = f2bf(acc[mt][nt][1]);
        w.z = f2bf(acc[mt][nt][2]); w.w = f2bf(acc[mt][nt][3]);
        long byte = ((long)(bh * 32 + ts) << 13) + d * 128 + ((key0 * 2) ^ ((d & 7) << 4));
        *(ushort4*)(O + byte) = w;
      }
  }
}

// ---------- flash attention v13: v9 body + hardened explicit sync ----------
__global__ __launch_bounds__(256, 4) void attn_k(const unsigned short* __restrict__ Qh,
                                                 const unsigned short* __restrict__ Kh,
                                                 const unsigned short* __restrict__ Vt,
                                                 const unsigned long long* __restrict__ MB,
                                                 unsigned short* __restrict__ Mha) {
  __shared__ __align__(16) char kv[2][16384];   // [buf][ K 8KB | V 8KB ]
  const int t = threadIdx.x, lane = t & 63, wv = t >> 6;
  const int id = blockIdx.x;                    // 1024 blocks, 8 XCDs
  const int logical = (id & 7) * 128 + (id >> 3);
  const int bh = logical >> 4, qt = logical & 15;
  const int b = bh >> 4, h = bh & 15;
  const int i0 = qt * 128 + wv * 32;
  const int lr = lane & 15, lg = lane >> 4;

  const unsigned short* Qp = Qh + ((long)bh * 2048 + i0) * 64;
  const char* Kg = (const char*)Kh + ((long)bh << 18);   // 32 tiles x 8KB
  const char* Vg = (const char*)Vt + ((long)bh << 18);
  const unsigned long long* mrow[2];
#pragma unroll
  for (int g = 0; g < 2; ++g) mrow[g] = MB + ((long)b * 2048 + i0 + g * 16 + lr) * 32;
  const int swz = (lr & 7) << 4;
  const int goff = wv * 2048 + lane * 16;
  const int loff = wv * 2048;

  // Q fragments, two groups (rows g*16 + lr)
  bf16x8 qf0[2], qf1[2];
#pragma unroll
  for (int g = 0; g < 2; ++g) {
    qf0[g] = *(const bf16x8*)(Qp + (g * 16 + lr) * 64 + lg * 8);
    qf1[g] = *(const bf16x8*)(Qp + (g * 16 + lr) * 64 + 32 + lg * 8);
  }

  bf16x8 ones;
#pragma unroll
  for (int i = 0; i < 8; ++i) ones[i] = (__bf16)1.0f;

  f32x4 zero = {0.f, 0.f, 0.f, 0.f};
  f32x4 oa[2][4];   // [g][dt]: O^T, lane holds O[d=dt*16+lg*4+r][q=g*16+lr]
#pragma unroll
  for (int g = 0; g < 2; ++g)
#pragma unroll
    for (int dt = 0; dt < 4; ++dt) oa[g][dt] = zero;
  float l[2] = {0.f, 0.f};

  auto stage = [&](int tile) {
    const char* kg = Kg + ((long)tile << 13);
    const char* vg = Vg + ((long)tile << 13);
    char* dst = &kv[tile & 1][0];
    gl16(kg + goff, dst + loff);
    gl16(kg + goff + 1024, dst + loff + 1024);
    gl16(vg + goff, dst + 8192 + loff);
    gl16(vg + goff + 1024, dst + 8192 + loff + 1024);
  };

  // prologue: stage tile 0 into buf 0
  stage(0);
  hard_sync();

  for (int ts = 0; ts < 32; ++ts) {
    const int cur = ts & 1;
    if (ts + 1 < 32) stage(ts + 1);   // writes kv[cur^1] while we read kv[cur]
    unsigned milo[2], mihi[2];
#pragma unroll
    for (int g = 0; g < 2; ++g) {
      unsigned long long msv = mrow[g][ts] >> (4 * lg);
      milo[g] = ~(unsigned)msv;
      mihi[g] = ~(unsigned)(msv >> 32);
    }
    const char* Kb = &kv[cur][0];
    const char* Vb = &kv[cur][8192];
    // ---- S^T = K Q^T + mask-C-init, both groups (K frags shared) ----
    f32x4 sv[2][4];
#pragma unroll
    for (int nt = 0; nt < 4; ++nt) {
      int key = nt * 16 + lr;
      int ksz = (key & 7) << 4;
      bf16x8 kf0 = *(const bf16x8*)(Kb + key * 128 + ((lg * 16) ^ ksz));
      bf16x8 kf1 = *(const bf16x8*)(Kb + key * 128 + ((lg * 16 + 64) ^ ksz));
#pragma unroll
      for (int g = 0; g < 2; ++g) {
        unsigned w = (nt < 2) ? milo[g] : mihi[g];
        f32x4 z;
#pragma unroll
        for (int r = 0; r < 4; ++r) {
          int mb = ((int)(w << (31 - ((nt & 1) * 16 + r)))) >> 31;  // bit -> all-ones
          z[r] = __int_as_float(mb & 0xC6EA6000);                   // -30000.0f
        }
        sv[g][nt] = mfma16(kf1, qf1[g], mfma16(kf0, qf0[g], z));
      }
    }
    // ---- p = exp2(s) (masked underflows to exact 0) ----
#pragma unroll
    for (int g = 0; g < 2; ++g)
#pragma unroll
      for (int nt = 0; nt < 4; ++nt)
#pragma unroll
        for (int r = 0; r < 4; ++r) sv[g][nt][r] = exp2fast(sv[g][nt][r]);
    // ---- pack + 4-lane-group transpose -> B-fragments ----
    union pu { unsigned w[4]; bf16x8 v; };
    pu pa0[2], pa1[2];
#pragma unroll
    for (int g = 0; g < 2; ++g) {
      unsigned u00 = cvtpk(sv[g][0][0], sv[g][0][1]), u01 = cvtpk(sv[g][0][2], sv[g][0][3]);
      unsigned u10 = cvtpk(sv[g][1][0], sv[g][1][1]), u11 = cvtpk(sv[g][1][2], sv[g][1][3]);
      unsigned u20 = cvtpk(sv[g][2][0], sv[g][2][1]), u21 = cvtpk(sv[g][2][2], sv[g][2][3]);
      unsigned u30 = cvtpk(sv[g][3][0], sv[g][3][1]), u31 = cvtpk(sv[g][3][2], sv[g][3][3]);
      swap32(u00, u10); swap16(u00, u10);
      swap32(u01, u11); swap16(u01, u11);
      pa0[g].w[0] = u00; pa0[g].w[1] = u01; pa0[g].w[2] = u10; pa0[g].w[3] = u11;
      swap32(u20, u30); swap16(u20, u30);
      swap32(u21, u31); swap16(u21, u31);
      pa1[g].w[0] = u20; pa1[g].w[1] = u21; pa1[g].w[2] = u30; pa1[g].w[3] = u31;
    }
    // ---- l += rowsum(P) via ones-MFMA ----
#pragma unroll
    for (int g = 0; g < 2; ++g) {
      f32x4 rs = mfma16(ones, pa1[g].v, mfma16(ones, pa0[g].v, zero));
      l[g] += rs[0];
    }
    // ---- O^T += V^T P^T ----
    __builtin_amdgcn_s_setprio(1);
#pragma unroll
    for (int dt = 0; dt < 4; ++dt) {
      int d = dt * 16 + lr;
      int vsz = (d & 7) << 4;
      bf16x8 vf0 = *(const bf16x8*)(Vb + d * 128 + ((lg * 16) ^ vsz));
      bf16x8 vf1 = *(const bf16x8*)(Vb + d * 128 + ((lg * 16 + 64) ^ vsz));
#pragma unroll
      for (int g = 0; g < 2; ++g)
        oa[g][dt] = mfma16(vf1, pa1[g].v, mfma16(vf0, pa0[g].v, oa[g][dt]));
    }
    __builtin_amdgcn_s_setprio(0);
    hard_sync();   // explicit vmcnt(0)+lgkmcnt(0) drain + barrier, fenced
  }

  // ---- epilogue: per-wave LDS transpose in kv scratch -> Mha[b][s][h*64+d] ----
  char* scr = &kv[0][0] + wv * 4096;   // 4KB per wave (final barrier passed)
#pragma unroll
  for (int g = 0; g < 2; ++g) {
    float inv = 1.f / l[g];
#pragma unroll
    for (int dt = 0; dt < 4; ++dt) {
      bf16x4 w;
#pragma unroll
      for (int r = 0; r < 4; ++r) w[r] = (__bf16)(oa[g][dt][r] * inv);
      *(bf16x4*)(scr + g * 2048 + lr * 128 + ((dt * 32 + lg * 8) ^ swz)) = w;
    }
  }
#pragma unroll
  for (int g = 0; g < 2; ++g) {
    unsigned short* Op = Mha + ((long)b * 2048 + i0 + g * 16 + lr) * 1024 + h * 64 + lg * 16;
    int b0 = g * 2048 + lr * 128 + ((lg * 32) ^ swz);
    int b1 = g * 2048 + lr * 128 + ((lg * 32 + 16) ^ swz);
    uint4 lo = *(const uint4*)(scr + b0), hi = *(const uint4*)(scr + b1);
    *(uint4*)(Op) = lo;
    *(uint4*)(Op + 8) = hi;
  }
}

extern "C" void kernel_launch(void* const* d_in, const int* in_sizes, int n_in,
                              void* d_out, int out_size, void* d_ws, size_t ws_size,
                              hipStream_t stream) {
  const float* q = (const float*)d_in[0];
  const float* k = (const float*)d_in[1];
  const float* v = (const float*)d_in[2];
  const int* mask = (const int*)d_in[3];
  const float* Wq = (const float*)d_in[4];
  const float* Wk = (const float*)d_in[5];
  const float* Wv = (const float*)d_in[6];
  const float* Wo = (const float*)d_in[7];
  (void)in_sizes; (void)n_in; (void)out_size; (void)ws_size;

  char* ws = (char*)d_ws;
  unsigned short* Wqt = (unsigned short*)(ws + (0ul << 20));
  unsigned short* Wkt = (unsigned short*)(ws + (2ul << 20));
  unsigned short* Wvt = (unsigned short*)(ws + (4ul << 20));
  unsigned short* Wot = (unsigned short*)(ws + (6ul << 20));
  unsigned long long* MBp = (unsigned long long*)(ws + (8ul << 20));
  unsigned short* Qh  = (unsigned short*)(ws + (10ul << 20));  // X2 first, then Qh
  unsigned short* Kh  = (unsigned short*)(ws + (26ul << 20));  // X3 first, then K tiles
  unsigned short* Vt  = (unsigned short*)(ws + (42ul << 20));
  unsigned short* Mha = (unsigned short*)(ws + (58ul << 20));  // X1 first, then Mha
  unsigned short* X1 = Mha, *X2 = Qh, *X3 = Kh;

  prep_k<<<81920, 256, 0, stream>>>(q, k, v, mask, Wq, Wk, Wv, Wo,
                                    Wqt, Wkt, Wvt, Wot, MBp, X1, X2, X3);

  gemm2_k<4><<<512, 256, 0, stream>>>(X3, Wvt, Vt, 1.0f);   // values -> V tiles
  gemm2_k<3><<<512, 256, 0, stream>>>(X2, Wkt, Kh, 1.0f);   // keys   -> K tiles (X3 dead)
  // Q scale = log2(e)/sqrt(64): softmax in exp2 domain
  gemm2_k<0><<<512, 256, 0, stream>>>(X1, Wqt, Qh, 0.125f * 1.44269504f);  // (X2 dead)

  attn_k<<<1024, 256, 0, stream>>>(Qh, Kh, Vt, MBp, Mha);   // (X1 dead)

  gemm2_k<2><<<512, 256, 0, stream>>>(Mha, Wot, d_out, 1.0f);
}